// Round 4
// baseline (380.484 us; speedup 1.0000x reference)
//
#include <hip/hip_runtime.h>
#include <hip/hip_bf16.h>

// Problem constants (reference): IN_DIM = HID = 64, K = 3, NCLS = 10.
// All compute fp32. Output fp32 (B*10).
//
// Pipeline (8 dispatches, R18):
//   k_histgemm : heterogeneous grid — u8-packed LDS histogram (PART_H=50176,
//                PH=2; hd at MCH=128 chunks, hs at MCHS=32 — offscan only
//                needs hs TOTALS, so chunk resolution there is wasted traffic)
//                + gemm1 tiles.  Hist write-out as packed u32.
//   k_offscan  : FUSED off+scan — 256 nodes/block, 32 node-slots x 8
//                chunk-slices; u64 byte-packed prefixes held in registers.
//   k_scan2    : 512-thread LDS exclusive scan; consumers add bsum[node>>8].
//   k_fill2    : u8-packed LDS cursors, PF*MCH = 512 blocks.
//   k_gather   : persistent 2048 blocks, LDS-free (R17 fused-GEMM reverted:
//                16-way LDS bank conflicts + 50% occupancy, −62 us).
//                Nontemporal loads for read-once streams (csr/rowptr/deg/
//                norm_d) and nontemporal stores (h/key): keep L2 for the
//                random m-rows — the gather is L2-miss-fabric bound
//                (~3.3 TB/s; R14 MLP ablation + R15 occupancy fix).
//   k_gemm64   : LDS-tiled layer-2 GEMM (restored).
//   k_tail     : per-graph top3 + bitonic sort-pool + classifier + gcnt.

#define PART_H 50176
#define QPART_H (PART_H / 4)
#define PART_F 25088
#define QUART_F (PART_F / 4)
#define MCH  128
#define MCHS 32

typedef float f4nt __attribute__((ext_vector_type(4)));

// ---------------- fused histogram + gemm1 (independent workloads, one grid)
__global__ void __launch_bounds__(256) k_histgemm(
    const int* __restrict__ esrc, const int* __restrict__ edst,
    unsigned char* __restrict__ hd, unsigned char* __restrict__ hs,
    const float* __restrict__ in, const float* __restrict__ W,
    float* __restrict__ mout, int N, int E, int PH, int histBlocks) {
  __shared__ float smem[12800];   // 51.2 KB union: hist counters / Wl+Ac
  const int t = threadIdx.x;
  if (blockIdx.x < histBlocks) {
    unsigned int* lc = (unsigned int*)smem;       // QPART_H u32 = 50176 B
    const int b = blockIdx.x;
    const int dblk = PH * MCH;
    const int a = (b < dblk) ? 0 : 1;
    const int r = a ? (b - dblk) : b;
    const int mch = a ? MCHS : MCH;
    const int p = r % PH;
    const int m = r / PH;
    const int* __restrict__ arr = a ? esrc : edst;
    unsigned char* __restrict__ outp = a ? hs : hd;
    const int base = p * PART_H;
    const int lim = min(PART_H, N - base);
    for (int i = t; i < QPART_H; i += 256) lc[i] = 0u;
    __syncthreads();
    const long long cb = (long long)m * E / mch;
    const long long ce = (long long)(m + 1) * E / mch;
    const long long a0 = min((cb + 3) & ~3LL, ce);
    const long long nv = (ce - a0) >> 2;
    for (long long e = cb + t; e < a0; e += 256) {
      int d = arr[e] - base;
      if ((unsigned)d < (unsigned)lim) atomicAdd(&lc[d >> 2], 1u << ((d & 3) * 8));
    }
    const int4* __restrict__ a4p = (const int4*)(arr + a0);
    for (long long i = t; i < nv; i += 256) {
      int4 v4 = a4p[i];
      int d;
      d = v4.x - base; if ((unsigned)d < (unsigned)lim) atomicAdd(&lc[d >> 2], 1u << ((d & 3) * 8));
      d = v4.y - base; if ((unsigned)d < (unsigned)lim) atomicAdd(&lc[d >> 2], 1u << ((d & 3) * 8));
      d = v4.z - base; if ((unsigned)d < (unsigned)lim) atomicAdd(&lc[d >> 2], 1u << ((d & 3) * 8));
      d = v4.w - base; if ((unsigned)d < (unsigned)lim) atomicAdd(&lc[d >> 2], 1u << ((d & 3) * 8));
    }
    for (long long e = a0 + (nv << 2) + t; e < ce; e += 256) {
      int d = arr[e] - base;
      if ((unsigned)d < (unsigned)lim) atomicAdd(&lc[d >> 2], 1u << ((d & 3) * 8));
    }
    __syncthreads();
    unsigned char* slice = outp + ((size_t)p * mch + m) * PART_H;
    unsigned int* slice4 = (unsigned int*)slice;
    const int lim4 = lim >> 2;
    for (int i = t; i < lim4; i += 256) slice4[i] = lc[i];     // 4 counts/store
    for (int i = (lim4 << 2) + t; i < lim; i += 256)
      slice[i] = (unsigned char)((lc[i >> 2] >> ((i & 3) * 8)) & 0xffu);
  } else {
    float* Wl = smem;             // 4096 floats
    float* Ac = smem + 4096;      // 64*136 = 8704 floats
    const int ch = (t & 7) * 8;
    const int nb = (t >> 3) * 4;
    for (int i = t; i < 1024; i += 256)
      ((float4*)Wl)[i] = ((const float4*)W)[i];
    const int gb = blockIdx.x - histBlocks;
    const int ng = gridDim.x - histBlocks;
    const int NT = (N + 127) >> 7;
    for (int tile = gb; tile < NT; tile += ng) {
      const int vbase = tile << 7;
      __syncthreads();
      for (int i = t; i < 2048; i += 256) {
        const int r = i >> 4;
        const int c = (i & 15) * 4;
        const int v = vbase + r;
        float4 val = make_float4(0.f, 0.f, 0.f, 0.f);
        if (v < N) val = *(const float4*)(in + (size_t)v * 64 + c);
        Ac[(c + 0) * 136 + r] = val.x;
        Ac[(c + 1) * 136 + r] = val.y;
        Ac[(c + 2) * 136 + r] = val.z;
        Ac[(c + 3) * 136 + r] = val.w;
      }
      __syncthreads();
      float acc[4][8];
#pragma unroll
      for (int j = 0; j < 4; ++j)
#pragma unroll
        for (int c = 0; c < 8; ++c) acc[j][c] = 0.f;
      for (int k = 0; k < 64; k += 4) {
#pragma unroll
        for (int kk = 0; kk < 4; ++kk) {
          const float4 aa = *(const float4*)&Ac[(k + kk) * 136 + nb];
          const float4 w0 = *(const float4*)&Wl[(k + kk) * 64 + ch];
          const float4 w1 = *(const float4*)&Wl[(k + kk) * 64 + ch + 4];
          const float an[4] = {aa.x, aa.y, aa.z, aa.w};
          const float wn[8] = {w0.x, w0.y, w0.z, w0.w, w1.x, w1.y, w1.z, w1.w};
#pragma unroll
          for (int j = 0; j < 4; ++j)
#pragma unroll
            for (int c = 0; c < 8; ++c)
              acc[j][c] = fmaf(an[j], wn[c], acc[j][c]);
        }
      }
#pragma unroll
      for (int j = 0; j < 4; ++j) {
        const int v = vbase + nb + j;
        if (v < N) {
          float4 o0, o1;
          o0.x = acc[j][0]; o0.y = acc[j][1]; o0.z = acc[j][2]; o0.w = acc[j][3];
          o1.x = acc[j][4]; o1.y = acc[j][5]; o1.z = acc[j][6]; o1.w = acc[j][7];
          *(float4*)(mout + (size_t)v * 64 + ch)     = o0;
          *(float4*)(mout + (size_t)v * 64 + ch + 4) = o1;
        }
      }
    }
  }
}

// ---- FUSED off+scan: 256 nodes/block.  32 node-slots (8 contiguous nodes,
// u64 byte-packed) x 8 chunk-slices (hd: 16 chunks each; hs: 4 chunks each).
// Chunk values held in registers between total pass and prefix-write pass.
// Byte-lane u64 adds are carry-safe: per-node degree <= 255; garbage tail
// bytes (v >= N) only carry upward into other garbage bytes (little-endian).
__global__ void __launch_bounds__(256) k_offscan(
    unsigned char* __restrict__ hd, const unsigned char* __restrict__ hs,
    int* __restrict__ deg_d, float* __restrict__ norm_s, float* __restrict__ norm_d,
    int* __restrict__ gstart, int* __restrict__ rowptr, int* __restrict__ bsum,
    int B, int N) {
  __shared__ unsigned long long part[32][8];   // deg slice totals
  __shared__ unsigned long long spart[32][8];  // src-deg slice totals
  __shared__ int sums[256];
  const int t = threadIdx.x;
  const int s = t >> 3;          // node slot (8 contiguous nodes)
  const int c = t & 7;           // chunk slice
  const int nb0 = blockIdx.x * 256;
  const int v0 = nb0 + s * 8;    // first node of this slot
  const int vt = nb0 + t;        // this thread's node for the scan phase
  if (vt < B) gstart[vt] = 0x7f7f7f7f;   // sentinel (>= N)
  // PART_H % 256 == 0: a block never straddles a hist partition.
  const size_t rb  = (size_t)(v0 / PART_H) * MCH  * PART_H + (size_t)(v0 % PART_H);
  const size_t rbs = (size_t)(v0 / PART_H) * MCHS * PART_H + (size_t)(v0 % PART_H);
  unsigned long long* __restrict__ hd8 = (unsigned long long*)(hd + rb);
  const unsigned long long* __restrict__ hs8 = (const unsigned long long*)(hs + rbs);
  const size_t st8 = PART_H / 8;
  const int m0 = c * 16;         // hd: 16 chunks per slice
  const int m0s = c * 4;         // hs: 4 chunks per slice
  const bool act = (v0 < N);
  unsigned long long vals[16];
  unsigned long long tsum = 0ull, hsum = 0ull;
  if (act) {
#pragma unroll
    for (int k = 0; k < 16; ++k) {
      vals[k] = hd8[(size_t)(m0 + k) * st8];
      tsum += vals[k];
    }
#pragma unroll
    for (int k = 0; k < 4; ++k) hsum += hs8[(size_t)(m0s + k) * st8];
  }
  part[s][c] = tsum;
  spart[s][c] = hsum;
  __syncthreads();
  // cross-slice base for this slice, then rewrite prefixes from registers
  if (act) {
    unsigned long long run = 0ull;
#pragma unroll
    for (int cc = 0; cc < 8; ++cc)
      if (cc < c) run += part[s][cc];
#pragma unroll
    for (int k = 0; k < 16; ++k) {
      const unsigned long long w = vals[k];
      hd8[(size_t)(m0 + k) * st8] = run;
      run += w;
    }
  }
  // per-node totals (read-only on part/spart; no extra barrier needed)
  unsigned long long dt = 0ull, ht = 0ull;
#pragma unroll
  for (int cc = 0; cc < 8; ++cc) {
    dt += part[t >> 3][cc];
    ht += spart[t >> 3][cc];
  }
  int dg = 0;
  if (vt < N) {
    dg = (int)((dt >> (8 * (t & 7))) & 0xffull);
    const int so = (int)((ht >> (8 * (t & 7))) & 0xffull);
    deg_d[vt] = dg;
    norm_d[vt] = rsqrtf((float)max(dg, 1));
    norm_s[vt] = rsqrtf((float)max(so, 1));
  }
  sums[t] = dg;
  __syncthreads();
  for (int off = 1; off < 256; off <<= 1) {
    int x = (t >= off) ? sums[t - off] : 0;
    __syncthreads();
    sums[t] += x;
    __syncthreads();
  }
  if (vt < N) rowptr[vt] = sums[t] - dg;     // exclusive prefix
  if (t == 255) bsum[blockIdx.x] = sums[255];
}

// 512-thread LDS exclusive scan (nscan <= 512)
__global__ void k_scan2(int* __restrict__ bsum, int nb) {
  __shared__ int sh[512];
  const int t = threadIdx.x;
  const int v = (t < nb) ? bsum[t] : 0;
  sh[t] = v;
  __syncthreads();
  for (int off = 1; off < 512; off <<= 1) {
    int x = (t >= off) ? sh[t - off] : 0;
    __syncthreads();
    sh[t] += x;
    __syncthreads();
  }
  if (t < nb) bsum[t] = sh[t] - v;
}

// --------------------------- fill (u8-packed LDS cursors, no global atomics)
__global__ void k_fill2(const int* __restrict__ esrc, const int* __restrict__ edst,
                        const unsigned char* __restrict__ hd, const int* __restrict__ rowptr,
                        const int* __restrict__ bsum, int* __restrict__ csr,
                        int N, int E, int PF) {
  __shared__ unsigned int cur4[QUART_F];
  const int b = blockIdx.x;
  const int p = b % PF;
  const int m = b / PF;
  const int base = p * PART_F;
  const int lim = min(PART_F, N - base);
  // PART_H == 2*PART_F: hist partition = p>>1, offset = (p&1)*PART_F
  const unsigned char* slice = hd + ((size_t)(p >> 1) * MCH + m) * PART_H
                                  + (size_t)(p & 1) * PART_F;
  const unsigned int* slice4 = (const unsigned int*)slice;
  for (int i = threadIdx.x; i < QUART_F; i += blockDim.x) cur4[i] = slice4[i];
  __syncthreads();
  const int* __restrict__ rp = rowptr + base;
  const long long cb = (long long)m * E / MCH;
  const long long ce = (long long)(m + 1) * E / MCH;
  const long long a0 = min((cb + 3) & ~3LL, ce);
  const long long nv = (ce - a0) >> 2;
  for (long long e = cb + threadIdx.x; e < a0; e += blockDim.x) {
    int d = edst[e] - base;
    if ((unsigned)d < (unsigned)lim) {
      unsigned int old = atomicAdd(&cur4[d >> 2], 1u << ((d & 3) * 8));
      csr[rp[d] + bsum[(base + d) >> 8] + ((old >> ((d & 3) * 8)) & 0xff)] = esrc[e];
    }
  }
  const int4* __restrict__ d4p = (const int4*)(edst + a0);
  const int4* __restrict__ s4p = (const int4*)(esrc + a0);
  for (long long i = threadIdx.x; i < nv; i += blockDim.x) {
    int4 d4 = d4p[i];
    int4 s4 = s4p[i];
    int d;
    d = d4.x - base;
    if ((unsigned)d < (unsigned)lim) {
      unsigned int old = atomicAdd(&cur4[d >> 2], 1u << ((d & 3) * 8));
      csr[rp[d] + bsum[(base + d) >> 8] + ((old >> ((d & 3) * 8)) & 0xff)] = s4.x;
    }
    d = d4.y - base;
    if ((unsigned)d < (unsigned)lim) {
      unsigned int old = atomicAdd(&cur4[d >> 2], 1u << ((d & 3) * 8));
      csr[rp[d] + bsum[(base + d) >> 8] + ((old >> ((d & 3) * 8)) & 0xff)] = s4.y;
    }
    d = d4.z - base;
    if ((unsigned)d < (unsigned)lim) {
      unsigned int old = atomicAdd(&cur4[d >> 2], 1u << ((d & 3) * 8));
      csr[rp[d] + bsum[(base + d) >> 8] + ((old >> ((d & 3) * 8)) & 0xff)] = s4.z;
    }
    d = d4.w - base;
    if ((unsigned)d < (unsigned)lim) {
      unsigned int old = atomicAdd(&cur4[d >> 2], 1u << ((d & 3) * 8));
      csr[rp[d] + bsum[(base + d) >> 8] + ((old >> ((d & 3) * 8)) & 0xff)] = s4.w;
    }
  }
  for (long long e = a0 + (nv << 2) + threadIdx.x; e < ce; e += blockDim.x) {
    int d = edst[e] - base;
    if ((unsigned)d < (unsigned)lim) {
      unsigned int old = atomicAdd(&cur4[d >> 2], 1u << ((d & 3) * 8));
      csr[rp[d] + bsum[(base + d) >> 8] + ((old >> ((d & 3) * 8)) & 0xff)] = esrc[e];
    }
  }
}

// ------------------------------------------------- (N,64) @ (64,64) GEMM
__global__ void __launch_bounds__(256) k_gemm64(
    const float* __restrict__ in, const float* __restrict__ norm,
    const float* __restrict__ W, float* __restrict__ out, int N) {
  __shared__ float Wl[4096];
  __shared__ float Ac[64 * 136];
  const int t = threadIdx.x;
  const int ch = (t & 7) * 8;
  const int nb = (t >> 3) * 4;
  for (int i = t; i < 1024; i += 256)
    ((float4*)Wl)[i] = ((const float4*)W)[i];
  const int NT = (N + 127) >> 7;
  for (int tile = blockIdx.x; tile < NT; tile += gridDim.x) {
    const int vbase = tile << 7;
    __syncthreads();
    for (int i = t; i < 2048; i += 256) {
      const int r = i >> 4;
      const int c = (i & 15) * 4;
      const int v = vbase + r;
      float4 val = make_float4(0.f, 0.f, 0.f, 0.f);
      if (v < N) val = *(const float4*)(in + (size_t)v * 64 + c);
      Ac[(c + 0) * 136 + r] = val.x;
      Ac[(c + 1) * 136 + r] = val.y;
      Ac[(c + 2) * 136 + r] = val.z;
      Ac[(c + 3) * 136 + r] = val.w;
    }
    __syncthreads();
    float acc[4][8];
#pragma unroll
    for (int j = 0; j < 4; ++j)
#pragma unroll
      for (int c = 0; c < 8; ++c) acc[j][c] = 0.f;
    for (int k = 0; k < 64; k += 4) {
#pragma unroll
      for (int kk = 0; kk < 4; ++kk) {
        const float4 aa = *(const float4*)&Ac[(k + kk) * 136 + nb];
        const float4 w0 = *(const float4*)&Wl[(k + kk) * 64 + ch];
        const float4 w1 = *(const float4*)&Wl[(k + kk) * 64 + ch + 4];
        const float an[4] = {aa.x, aa.y, aa.z, aa.w};
        const float wn[8] = {w0.x, w0.y, w0.z, w0.w, w1.x, w1.y, w1.z, w1.w};
#pragma unroll
        for (int j = 0; j < 4; ++j)
#pragma unroll
          for (int c = 0; c < 8; ++c)
            acc[j][c] = fmaf(an[j], wn[c], acc[j][c]);
      }
    }
#pragma unroll
    for (int j = 0; j < 4; ++j) {
      const int v = vbase + nb + j;
      if (v < N) {
        const float nm = norm[v];
        float4 o0, o1;
        o0.x = acc[j][0] * nm; o0.y = acc[j][1] * nm;
        o0.z = acc[j][2] * nm; o0.w = acc[j][3] * nm;
        o1.x = acc[j][4] * nm; o1.y = acc[j][5] * nm;
        o1.z = acc[j][6] * nm; o1.w = acc[j][7] * nm;
        *(float4*)(out + (size_t)v * 64 + ch)     = o0;
        *(float4*)(out + (size_t)v * 64 + ch + 4) = o1;
      }
    }
  }
}

// ---------------------------------------- CSR gather + fused epilogue
// PERSISTENT grid; one node per wave per iteration (8-group x 8-lane layout).
// Nontemporal loads for read-once streams, nontemporal stores for outputs:
// keeps L2 lines for the randomly gathered m rows (the bound resource).
__global__ void k_gather(const float* __restrict__ m, const int* __restrict__ rowptr,
                         const int* __restrict__ bsum,
                         const int* __restrict__ deg, const float* __restrict__ norm_d,
                         const float* __restrict__ bias, const int* __restrict__ csr,
                         const float* __restrict__ nsrc,
                         const int* __restrict__ gid, int* __restrict__ gstart,
                         float* __restrict__ h, float* __restrict__ key, int N) {
  const int wpb = blockDim.x >> 6;
  const int nwaves = gridDim.x * wpb;
  const int lane = threadIdx.x & 63;
  const int chb = (lane & 7) * 8;   // channel base (8 ch/lane)
  const int grp = lane >> 3;        // 8 edge subgroups
  const float4 b0 = *(const float4*)(bias + chb);
  const float4 b1 = *(const float4*)(bias + chb + 4);
  for (int w = blockIdx.x * wpb + (threadIdx.x >> 6); w < N; w += nwaves) {
    if (gid != nullptr && lane == 0) {
      int g = gid[w];
      if (w == 0 || gid[w - 1] != g) gstart[g] = w;
    }
    const int start = __builtin_nontemporal_load(rowptr + w) + bsum[w >> 8];
    const int cnt = __builtin_nontemporal_load(deg + w);
    float4 a00 = make_float4(0.f, 0.f, 0.f, 0.f);
    float4 a01 = make_float4(0.f, 0.f, 0.f, 0.f);
    float4 a10 = make_float4(0.f, 0.f, 0.f, 0.f);
    float4 a11 = make_float4(0.f, 0.f, 0.f, 0.f);
    int i = grp;
    if (nsrc != nullptr) {
      for (; i + 8 < cnt; i += 16) {
        int s0 = __builtin_nontemporal_load(csr + start + i);
        int s1 = __builtin_nontemporal_load(csr + start + i + 8);
        float n0 = nsrc[s0], n1 = nsrc[s1];
        const float* r0 = m + (size_t)s0 * 64 + chb;
        const float* r1 = m + (size_t)s1 * 64 + chb;
        const float4 v00 = *(const float4*)r0;
        const float4 v01 = *(const float4*)(r0 + 4);
        const float4 v10 = *(const float4*)r1;
        const float4 v11 = *(const float4*)(r1 + 4);
        a00.x = fmaf(v00.x, n0, a00.x); a00.y = fmaf(v00.y, n0, a00.y);
        a00.z = fmaf(v00.z, n0, a00.z); a00.w = fmaf(v00.w, n0, a00.w);
        a01.x = fmaf(v01.x, n0, a01.x); a01.y = fmaf(v01.y, n0, a01.y);
        a01.z = fmaf(v01.z, n0, a01.z); a01.w = fmaf(v01.w, n0, a01.w);
        a10.x = fmaf(v10.x, n1, a10.x); a10.y = fmaf(v10.y, n1, a10.y);
        a10.z = fmaf(v10.z, n1, a10.z); a10.w = fmaf(v10.w, n1, a10.w);
        a11.x = fmaf(v11.x, n1, a11.x); a11.y = fmaf(v11.y, n1, a11.y);
        a11.w = fmaf(v11.w, n1, a11.w); a11.z = fmaf(v11.z, n1, a11.z);
      }
      if (i < cnt) {
        int s0 = __builtin_nontemporal_load(csr + start + i);
        float n0 = nsrc[s0];
        const float* r0 = m + (size_t)s0 * 64 + chb;
        const float4 v00 = *(const float4*)r0;
        const float4 v01 = *(const float4*)(r0 + 4);
        a00.x = fmaf(v00.x, n0, a00.x); a00.y = fmaf(v00.y, n0, a00.y);
        a00.z = fmaf(v00.z, n0, a00.z); a00.w = fmaf(v00.w, n0, a00.w);
        a01.x = fmaf(v01.x, n0, a01.x); a01.y = fmaf(v01.y, n0, a01.y);
        a01.z = fmaf(v01.z, n0, a01.z); a01.w = fmaf(v01.w, n0, a01.w);
      }
    } else {
      for (; i + 8 < cnt; i += 16) {
        int s0 = __builtin_nontemporal_load(csr + start + i);
        int s1 = __builtin_nontemporal_load(csr + start + i + 8);
        const float* r0 = m + (size_t)s0 * 64 + chb;
        const float* r1 = m + (size_t)s1 * 64 + chb;
        const float4 v00 = *(const float4*)r0;
        const float4 v01 = *(const float4*)(r0 + 4);
        const float4 v10 = *(const float4*)r1;
        const float4 v11 = *(const float4*)(r1 + 4);
        a00.x += v00.x; a00.y += v00.y; a00.z += v00.z; a00.w += v00.w;
        a01.x += v01.x; a01.y += v01.y; a01.z += v01.z; a01.w += v01.w;
        a10.x += v10.x; a10.y += v10.y; a10.z += v10.z; a10.w += v10.w;
        a11.x += v11.x; a11.y += v11.y; a11.z += v11.z; a11.w += v11.w;
      }
      if (i < cnt) {
        int s0 = __builtin_nontemporal_load(csr + start + i);
        const float* r0 = m + (size_t)s0 * 64 + chb;
        const float4 v00 = *(const float4*)r0;
        const float4 v01 = *(const float4*)(r0 + 4);
        a00.x += v00.x; a00.y += v00.y; a00.z += v00.z; a00.w += v00.w;
        a01.x += v01.x; a01.y += v01.y; a01.z += v01.z; a01.w += v01.w;
      }
    }
    a00.x += a10.x; a00.y += a10.y; a00.z += a10.z; a00.w += a10.w;
    a01.x += a11.x; a01.y += a11.y; a01.z += a11.z; a01.w += a11.w;
#pragma unroll
    for (int off = 8; off <= 32; off <<= 1) {
      a00.x += __shfl_xor(a00.x, off, 64);
      a00.y += __shfl_xor(a00.y, off, 64);
      a00.z += __shfl_xor(a00.z, off, 64);
      a00.w += __shfl_xor(a00.w, off, 64);
      a01.x += __shfl_xor(a01.x, off, 64);
      a01.y += __shfl_xor(a01.y, off, 64);
      a01.z += __shfl_xor(a01.z, off, 64);
      a01.w += __shfl_xor(a01.w, off, 64);
    }
    const float nd = __builtin_nontemporal_load(norm_d + w);
    float4 o0, o1;
    o0.x = fmaxf(fmaf(a00.x, nd, b0.x), 0.f);
    o0.y = fmaxf(fmaf(a00.y, nd, b0.y), 0.f);
    o0.z = fmaxf(fmaf(a00.z, nd, b0.z), 0.f);
    o0.w = fmaxf(fmaf(a00.w, nd, b0.w), 0.f);
    o1.x = fmaxf(fmaf(a01.x, nd, b1.x), 0.f);
    o1.y = fmaxf(fmaf(a01.y, nd, b1.y), 0.f);
    o1.z = fmaxf(fmaf(a01.z, nd, b1.z), 0.f);
    o1.w = fmaxf(fmaf(a01.w, nd, b1.w), 0.f);
    if (grp == 0) {
      __builtin_nontemporal_store(*(const f4nt*)&o0, (f4nt*)(h + (size_t)w * 64 + chb));
      __builtin_nontemporal_store(*(const f4nt*)&o1, (f4nt*)(h + (size_t)w * 64 + chb + 4));
    }
    if (key != nullptr) {
      float mx = fmaxf(fmaxf(fmaxf(o0.x, o0.y), fmaxf(o0.z, o0.w)),
                       fmaxf(fmaxf(o1.x, o1.y), fmaxf(o1.z, o1.w)));
#pragma unroll
      for (int off = 1; off < 8; off <<= 1) mx = fmaxf(mx, __shfl_xor(mx, off, 64));
      if (lane == 0) __builtin_nontemporal_store(mx, key + w);
    }
  }
}

// ---------------- fused tail: top3 + bitonic sort-pool + classifier + gcnt
__global__ void __launch_bounds__(256) k_tail(
    const float* __restrict__ key, const int* __restrict__ gstart,
    const float* __restrict__ h,
    const float* __restrict__ cw, const float* __restrict__ cb,
    const float* __restrict__ Wc, const float* __restrict__ bc,
    float* __restrict__ out, int B, int N) {
  __shared__ int sel[3];
  __shared__ float prow[192];
  const int b = blockIdx.x;
  const int wid = threadIdx.x >> 6;
  const int lane = threadIdx.x & 63;

  if (wid == 0) {
    const int gs = gstart[b];
    int g2 = b + 1;
    while (g2 < B && gstart[g2] >= N) ++g2;   // skip empty graphs (sentinel)
    const int ns = (g2 < B) ? gstart[g2] : N;
    const int s = gs;
    const int c = (gs < N) ? (ns - gs) : 0;
    float v0 = -1.f, v1 = -1.f, v2 = -1.f;
    int i0 = 0x7fffffff, i1 = 0x7fffffff, i2 = 0x7fffffff;
    for (int i = s + lane; i < s + c; i += 64) {
      float kv = key[i];
      if (kv > v0 || (kv == v0 && i < i0)) {
        v2 = v1; i2 = i1; v1 = v0; i1 = i0; v0 = kv; i0 = i;
      } else if (kv > v1 || (kv == v1 && i < i1)) {
        v2 = v1; i2 = i1; v1 = kv; i1 = i;
      } else if (kv > v2 || (kv == v2 && i < i2)) {
        v2 = kv; i2 = i;
      }
    }
    int ptr = 0;
    for (int r = 0; r < 3; ++r) {
      float mv = (ptr == 0) ? v0 : (ptr == 1) ? v1 : (ptr == 2) ? v2 : -1.f;
      int   mi = (ptr == 0) ? i0 : (ptr == 1) ? i1 : (ptr == 2) ? i2 : 0x7fffffff;
      float bv = mv; int bi = mi;
#pragma unroll
      for (int off = 32; off; off >>= 1) {
        float ov = __shfl_xor(bv, off, 64);
        int   oi = __shfl_xor(bi, off, 64);
        if (ov > bv || (ov == bv && oi < bi)) { bv = ov; bi = oi; }
      }
      if (bi == mi && ptr < 3) ptr++;             // winner's owner pops
      if (lane == 0) sel[r] = (bi == 0x7fffffff) ? -1 : bi;
    }
  }
  __syncthreads();
  if (wid < 3) {
    int node = sel[wid];
    float v = 0.f;
    if (node >= 0) {
      v = h[(size_t)node * 64 + lane];
      for (int k2 = 2; k2 <= 64; k2 <<= 1) {
        for (int j = k2 >> 1; j > 0; j >>= 1) {
          float o = __shfl_xor(v, j, 64);
          bool up = ((lane & k2) == 0);
          bool lower = ((lane & j) == 0);
          v = (lower == up) ? fminf(v, o) : fmaxf(v, o);
        }
      }
    }
    prow[wid * 64 + lane] = v;
  }
  __syncthreads();
  if (wid == 0) {
    float y = cb[lane];
    for (int j = 0; j < 192; ++j) y = fmaf(prow[j], cw[lane * 192 + j], y);
    float ry = fmaxf(y, 0.f);
    for (int c = 0; c < 10; ++c) {
      float s = ry * Wc[lane * 10 + c];
#pragma unroll
      for (int off = 32; off; off >>= 1) s += __shfl_xor(s, off, 64);
      if (lane == 0) out[b * 10 + c] = s + bc[c];
    }
  }
}

// ================================================================ launch
extern "C" void kernel_launch(void* const* d_in, const int* in_sizes, int n_in,
                              void* d_out, int out_size, void* d_ws, size_t ws_size,
                              hipStream_t stream) {
  const float* features = (const float*)d_in[0];
  const int*   esrc     = (const int*)d_in[1];
  const int*   edst     = (const int*)d_in[2];
  const int*   gid      = (const int*)d_in[3];
  const float* W1 = (const float*)d_in[5];
  const float* b1 = (const float*)d_in[6];
  const float* W2 = (const float*)d_in[7];
  const float* b2 = (const float*)d_in[8];
  const float* cw = (const float*)d_in[9];
  const float* cb = (const float*)d_in[10];
  const float* Wc = (const float*)d_in[11];
  const float* bc = (const float*)d_in[12];
  float* out = (float*)d_out;

  const int N = in_sizes[0] / 64;
  const int E = in_sizes[1];
  const int B = out_size / 10;
  const size_t N64 = (size_t)N * 64;
  const int nscan = (N + 255) / 256;            // 391 for N=100k (<= 512)
  const int PH = (N + PART_H - 1) / PART_H;     // 2 for N=100k
  const int PF = (N + PART_F - 1) / PART_F;     // 4 for N=100k
  const size_t HSZD = (size_t)PH * MCH  * PART_H; // hd bytes (~12.8 MB)
  const size_t HSZS = (size_t)PH * MCHS * PART_H; // hs bytes (~3.2 MB)
  const int NT = (N + 127) / 128;               // gemm tiles
  const int histBlocks = PH * (MCH + MCHS);     // 320

  // workspace carve-up (fully disjoint).
  float* bufA   = (float*)d_ws;            // N*64 : m1 -> m2
  float* bufB   = bufA + N64;              // N*64 : h1 -> h2
  int*   deg_d  = (int*)(bufB + N64);      // N
  float* norm_s = (float*)(deg_d + N);     // N
  float* norm_d = norm_s + N;              // N
  float* key    = norm_d + N;              // N
  int*   rowptr = (int*)(key + N);         // N
  int*   csr    = rowptr + N;              // E
  int*   bsum   = csr + E;                 // <=512
  int*   gstart = bsum + 512;              // B
  // align hd to 16 B for the u64-vectorized offset pass in k_offscan
  unsigned char* hd = (unsigned char*)(((size_t)(gstart + B) + 15) & ~(size_t)15);
  unsigned char* hs = hd + HSZD;                     // HSZS u8

  const int TB = 256;

  // ---- CSR build overlapped with gemm1 (un-normed; norm_s applied in gather1)
  k_histgemm<<<histBlocks + NT, TB, 0, stream>>>(esrc, edst, hd, hs,
                                                 features, W1, bufA,
                                                 N, E, PH, histBlocks);
  k_offscan<<<nscan, 256, 0, stream>>>(hd, hs, deg_d, norm_s, norm_d,
                                       gstart, rowptr, bsum, B, N);
  k_scan2<<<1, 512, 0, stream>>>(bsum, nscan);
  k_fill2<<<PF * MCH, TB, 0, stream>>>(esrc, edst, hd, rowptr, bsum, csr, N, E, PF);

  // ---- gathers: persistent grid (8 blocks/CU resident on 256 CUs)
  const int GB = 2048;

  // ---- layer 1 gather (applies norm_s per source)
  k_gather<<<GB, TB, 0, stream>>>(bufA, rowptr, bsum, deg_d, norm_d, b1,
                                  csr, norm_s, nullptr, nullptr,
                                  bufB, nullptr, N);

  // ---- layer 2
  k_gemm64<<<NT, TB, 0, stream>>>(bufB, norm_s, W2, bufA, N);
  k_gather<<<GB, TB, 0, stream>>>(bufA, rowptr, bsum, deg_d, norm_d, b2,
                                  csr, nullptr, gid, gstart,
                                  bufB, key, N);

  // ---- pooling + classifier (gcnt fused into tail)
  k_tail<<<B, TB, 0, stream>>>(key, gstart, bufB, cw, cb, Wc, bc, out, B, N);
}

// Round 5
// 286.509 us; speedup vs baseline: 1.3280x; 1.3280x over previous
//
#include <hip/hip_runtime.h>
#include <hip/hip_bf16.h>

// Problem constants (reference): IN_DIM = HID = 64, K = 3, NCLS = 10.
// All compute fp32. Output fp32 (B*10).
//
// Pipeline (8 dispatches, R19):
//   k_histgemm : heterogeneous grid — u8-packed LDS histogram (PART_H=50176,
//                PH=2; hd at MCH=128 chunks, hs at MCHS=32) + gemm1 tiles.
//                LDS zero + write-out as uint4 (beyond-lim counters are 0).
//   k_offscan  : FUSED off+scan — 256 nodes/block, 32 node-slots x 8
//                chunk-slices; u64 byte-packed prefixes held in registers.
//   k_scan2    : 512-thread LDS exclusive scan; consumers add bsum[node>>8].
//   k_fill2    : u8-packed LDS cursors, PF*MCH = 512 blocks.
//   k_gather   : persistent 2048 blocks, plain loads/stores (R18 nontemporal
//                hints REVERTED: −85% on this chip — never hint the hot
//                stream).  Gather is at the ~3.3 TB/s L2-miss fabric floor
//                (ledger: MLP-double neutral, occupancy +9%, nt −85%).
//                gather2 stores KEY ONLY — h2 (25.6 MB write) eliminated;
//                k_tail re-gathers the 3 selected rows per graph.
//   k_gemm64   : LDS-tiled layer-2 GEMM.
//   k_tail     : per-graph top3 + re-gather of selected rows + bitonic
//                sort-pool + classifier + fused gcnt.

#define PART_H 50176
#define QPART_H (PART_H / 4)
#define PART_F 25088
#define QUART_F (PART_F / 4)
#define MCH  128
#define MCHS 32

// ---------------- fused histogram + gemm1 (independent workloads, one grid)
__global__ void __launch_bounds__(256) k_histgemm(
    const int* __restrict__ esrc, const int* __restrict__ edst,
    unsigned char* __restrict__ hd, unsigned char* __restrict__ hs,
    const float* __restrict__ in, const float* __restrict__ W,
    float* __restrict__ mout, int N, int E, int PH, int histBlocks) {
  __shared__ float smem[12800];   // 51.2 KB union: hist counters / Wl+Ac
  const int t = threadIdx.x;
  if (blockIdx.x < histBlocks) {
    unsigned int* lc = (unsigned int*)smem;       // QPART_H u32 = 50176 B
    const int b = blockIdx.x;
    const int dblk = PH * MCH;
    const int a = (b < dblk) ? 0 : 1;
    const int r = a ? (b - dblk) : b;
    const int mch = a ? MCHS : MCH;
    const int p = r % PH;
    const int m = r / PH;
    const int* __restrict__ arr = a ? esrc : edst;
    unsigned char* __restrict__ outp = a ? hs : hd;
    const int base = p * PART_H;
    const int lim = min(PART_H, N - base);
    {
      uint4 z = make_uint4(0u, 0u, 0u, 0u);
      uint4* lc16 = (uint4*)lc;
      for (int i = t; i < QPART_H / 4; i += 256) lc16[i] = z;
    }
    __syncthreads();
    const long long cb = (long long)m * E / mch;
    const long long ce = (long long)(m + 1) * E / mch;
    const long long a0 = min((cb + 3) & ~3LL, ce);
    const long long nv = (ce - a0) >> 2;
    for (long long e = cb + t; e < a0; e += 256) {
      int d = arr[e] - base;
      if ((unsigned)d < (unsigned)lim) atomicAdd(&lc[d >> 2], 1u << ((d & 3) * 8));
    }
    const int4* __restrict__ a4p = (const int4*)(arr + a0);
    for (long long i = t; i < nv; i += 256) {
      int4 v4 = a4p[i];
      int d;
      d = v4.x - base; if ((unsigned)d < (unsigned)lim) atomicAdd(&lc[d >> 2], 1u << ((d & 3) * 8));
      d = v4.y - base; if ((unsigned)d < (unsigned)lim) atomicAdd(&lc[d >> 2], 1u << ((d & 3) * 8));
      d = v4.z - base; if ((unsigned)d < (unsigned)lim) atomicAdd(&lc[d >> 2], 1u << ((d & 3) * 8));
      d = v4.w - base; if ((unsigned)d < (unsigned)lim) atomicAdd(&lc[d >> 2], 1u << ((d & 3) * 8));
    }
    for (long long e = a0 + (nv << 2) + t; e < ce; e += 256) {
      int d = arr[e] - base;
      if ((unsigned)d < (unsigned)lim) atomicAdd(&lc[d >> 2], 1u << ((d & 3) * 8));
    }
    __syncthreads();
    // full-slice uint4 write-out: counters beyond lim are zero (guarded
    // atomics) so writing the whole PART_H slice is safe and branch-free.
    unsigned char* slice = outp + ((size_t)p * mch + m) * PART_H;
    uint4* slice16 = (uint4*)slice;
    const uint4* lc16 = (const uint4*)lc;
    for (int i = t; i < QPART_H / 4; i += 256) slice16[i] = lc16[i];
  } else {
    float* Wl = smem;             // 4096 floats
    float* Ac = smem + 4096;      // 64*136 = 8704 floats
    const int ch = (t & 7) * 8;
    const int nb = (t >> 3) * 4;
    for (int i = t; i < 1024; i += 256)
      ((float4*)Wl)[i] = ((const float4*)W)[i];
    const int gb = blockIdx.x - histBlocks;
    const int ng = gridDim.x - histBlocks;
    const int NT = (N + 127) >> 7;
    for (int tile = gb; tile < NT; tile += ng) {
      const int vbase = tile << 7;
      __syncthreads();
      for (int i = t; i < 2048; i += 256) {
        const int r = i >> 4;
        const int c = (i & 15) * 4;
        const int v = vbase + r;
        float4 val = make_float4(0.f, 0.f, 0.f, 0.f);
        if (v < N) val = *(const float4*)(in + (size_t)v * 64 + c);
        Ac[(c + 0) * 136 + r] = val.x;
        Ac[(c + 1) * 136 + r] = val.y;
        Ac[(c + 2) * 136 + r] = val.z;
        Ac[(c + 3) * 136 + r] = val.w;
      }
      __syncthreads();
      float acc[4][8];
#pragma unroll
      for (int j = 0; j < 4; ++j)
#pragma unroll
        for (int c = 0; c < 8; ++c) acc[j][c] = 0.f;
      for (int k = 0; k < 64; k += 4) {
#pragma unroll
        for (int kk = 0; kk < 4; ++kk) {
          const float4 aa = *(const float4*)&Ac[(k + kk) * 136 + nb];
          const float4 w0 = *(const float4*)&Wl[(k + kk) * 64 + ch];
          const float4 w1 = *(const float4*)&Wl[(k + kk) * 64 + ch + 4];
          const float an[4] = {aa.x, aa.y, aa.z, aa.w};
          const float wn[8] = {w0.x, w0.y, w0.z, w0.w, w1.x, w1.y, w1.z, w1.w};
#pragma unroll
          for (int j = 0; j < 4; ++j)
#pragma unroll
            for (int c = 0; c < 8; ++c)
              acc[j][c] = fmaf(an[j], wn[c], acc[j][c]);
        }
      }
#pragma unroll
      for (int j = 0; j < 4; ++j) {
        const int v = vbase + nb + j;
        if (v < N) {
          float4 o0, o1;
          o0.x = acc[j][0]; o0.y = acc[j][1]; o0.z = acc[j][2]; o0.w = acc[j][3];
          o1.x = acc[j][4]; o1.y = acc[j][5]; o1.z = acc[j][6]; o1.w = acc[j][7];
          *(float4*)(mout + (size_t)v * 64 + ch)     = o0;
          *(float4*)(mout + (size_t)v * 64 + ch + 4) = o1;
        }
      }
    }
  }
}

// ---- FUSED off+scan: 256 nodes/block.  32 node-slots (8 contiguous nodes,
// u64 byte-packed) x 8 chunk-slices (hd: 16 chunks each; hs: 4 chunks each).
// Chunk values held in registers between total pass and prefix-write pass.
// Byte-lane u64 adds are carry-safe: per-node degree <= 255; garbage tail
// bytes (v >= N) only carry upward into other garbage bytes (little-endian).
__global__ void __launch_bounds__(256) k_offscan(
    unsigned char* __restrict__ hd, const unsigned char* __restrict__ hs,
    int* __restrict__ deg_d, float* __restrict__ norm_s, float* __restrict__ norm_d,
    int* __restrict__ gstart, int* __restrict__ rowptr, int* __restrict__ bsum,
    int B, int N) {
  __shared__ unsigned long long part[32][8];   // deg slice totals
  __shared__ unsigned long long spart[32][8];  // src-deg slice totals
  __shared__ int sums[256];
  const int t = threadIdx.x;
  const int s = t >> 3;          // node slot (8 contiguous nodes)
  const int c = t & 7;           // chunk slice
  const int nb0 = blockIdx.x * 256;
  const int v0 = nb0 + s * 8;    // first node of this slot
  const int vt = nb0 + t;        // this thread's node for the scan phase
  if (vt < B) gstart[vt] = 0x7f7f7f7f;   // sentinel (>= N)
  // PART_H % 256 == 0: a block never straddles a hist partition.
  const size_t rb  = (size_t)(v0 / PART_H) * MCH  * PART_H + (size_t)(v0 % PART_H);
  const size_t rbs = (size_t)(v0 / PART_H) * MCHS * PART_H + (size_t)(v0 % PART_H);
  unsigned long long* __restrict__ hd8 = (unsigned long long*)(hd + rb);
  const unsigned long long* __restrict__ hs8 = (const unsigned long long*)(hs + rbs);
  const size_t st8 = PART_H / 8;
  const int m0 = c * 16;         // hd: 16 chunks per slice
  const int m0s = c * 4;         // hs: 4 chunks per slice
  const bool act = (v0 < N);
  unsigned long long vals[16];
  unsigned long long tsum = 0ull, hsum = 0ull;
  if (act) {
#pragma unroll
    for (int k = 0; k < 16; ++k) {
      vals[k] = hd8[(size_t)(m0 + k) * st8];
      tsum += vals[k];
    }
#pragma unroll
    for (int k = 0; k < 4; ++k) hsum += hs8[(size_t)(m0s + k) * st8];
  }
  part[s][c] = tsum;
  spart[s][c] = hsum;
  __syncthreads();
  // cross-slice base for this slice, then rewrite prefixes from registers
  if (act) {
    unsigned long long run = 0ull;
#pragma unroll
    for (int cc = 0; cc < 8; ++cc)
      if (cc < c) run += part[s][cc];
#pragma unroll
    for (int k = 0; k < 16; ++k) {
      const unsigned long long w = vals[k];
      hd8[(size_t)(m0 + k) * st8] = run;
      run += w;
    }
  }
  // per-node totals (read-only on part/spart; no extra barrier needed)
  unsigned long long dt = 0ull, ht = 0ull;
#pragma unroll
  for (int cc = 0; cc < 8; ++cc) {
    dt += part[t >> 3][cc];
    ht += spart[t >> 3][cc];
  }
  int dg = 0;
  if (vt < N) {
    dg = (int)((dt >> (8 * (t & 7))) & 0xffull);
    const int so = (int)((ht >> (8 * (t & 7))) & 0xffull);
    deg_d[vt] = dg;
    norm_d[vt] = rsqrtf((float)max(dg, 1));
    norm_s[vt] = rsqrtf((float)max(so, 1));
  }
  sums[t] = dg;
  __syncthreads();
  for (int off = 1; off < 256; off <<= 1) {
    int x = (t >= off) ? sums[t - off] : 0;
    __syncthreads();
    sums[t] += x;
    __syncthreads();
  }
  if (vt < N) rowptr[vt] = sums[t] - dg;     // exclusive prefix
  if (t == 255) bsum[blockIdx.x] = sums[255];
}

// 512-thread LDS exclusive scan (nscan <= 512)
__global__ void k_scan2(int* __restrict__ bsum, int nb) {
  __shared__ int sh[512];
  const int t = threadIdx.x;
  const int v = (t < nb) ? bsum[t] : 0;
  sh[t] = v;
  __syncthreads();
  for (int off = 1; off < 512; off <<= 1) {
    int x = (t >= off) ? sh[t - off] : 0;
    __syncthreads();
    sh[t] += x;
    __syncthreads();
  }
  if (t < nb) bsum[t] = sh[t] - v;
}

// --------------------------- fill (u8-packed LDS cursors, no global atomics)
__global__ void k_fill2(const int* __restrict__ esrc, const int* __restrict__ edst,
                        const unsigned char* __restrict__ hd, const int* __restrict__ rowptr,
                        const int* __restrict__ bsum, int* __restrict__ csr,
                        int N, int E, int PF) {
  __shared__ unsigned int cur4[QUART_F];
  const int b = blockIdx.x;
  const int p = b % PF;
  const int m = b / PF;
  const int base = p * PART_F;
  const int lim = min(PART_F, N - base);
  // PART_H == 2*PART_F: hist partition = p>>1, offset = (p&1)*PART_F
  const unsigned char* slice = hd + ((size_t)(p >> 1) * MCH + m) * PART_H
                                  + (size_t)(p & 1) * PART_F;
  const unsigned int* slice4 = (const unsigned int*)slice;
  for (int i = threadIdx.x; i < QUART_F; i += blockDim.x) cur4[i] = slice4[i];
  __syncthreads();
  const int* __restrict__ rp = rowptr + base;
  const long long cb = (long long)m * E / MCH;
  const long long ce = (long long)(m + 1) * E / MCH;
  const long long a0 = min((cb + 3) & ~3LL, ce);
  const long long nv = (ce - a0) >> 2;
  for (long long e = cb + threadIdx.x; e < a0; e += blockDim.x) {
    int d = edst[e] - base;
    if ((unsigned)d < (unsigned)lim) {
      unsigned int old = atomicAdd(&cur4[d >> 2], 1u << ((d & 3) * 8));
      csr[rp[d] + bsum[(base + d) >> 8] + ((old >> ((d & 3) * 8)) & 0xff)] = esrc[e];
    }
  }
  const int4* __restrict__ d4p = (const int4*)(edst + a0);
  const int4* __restrict__ s4p = (const int4*)(esrc + a0);
  for (long long i = threadIdx.x; i < nv; i += blockDim.x) {
    int4 d4 = d4p[i];
    int4 s4 = s4p[i];
    int d;
    d = d4.x - base;
    if ((unsigned)d < (unsigned)lim) {
      unsigned int old = atomicAdd(&cur4[d >> 2], 1u << ((d & 3) * 8));
      csr[rp[d] + bsum[(base + d) >> 8] + ((old >> ((d & 3) * 8)) & 0xff)] = s4.x;
    }
    d = d4.y - base;
    if ((unsigned)d < (unsigned)lim) {
      unsigned int old = atomicAdd(&cur4[d >> 2], 1u << ((d & 3) * 8));
      csr[rp[d] + bsum[(base + d) >> 8] + ((old >> ((d & 3) * 8)) & 0xff)] = s4.y;
    }
    d = d4.z - base;
    if ((unsigned)d < (unsigned)lim) {
      unsigned int old = atomicAdd(&cur4[d >> 2], 1u << ((d & 3) * 8));
      csr[rp[d] + bsum[(base + d) >> 8] + ((old >> ((d & 3) * 8)) & 0xff)] = s4.z;
    }
    d = d4.w - base;
    if ((unsigned)d < (unsigned)lim) {
      unsigned int old = atomicAdd(&cur4[d >> 2], 1u << ((d & 3) * 8));
      csr[rp[d] + bsum[(base + d) >> 8] + ((old >> ((d & 3) * 8)) & 0xff)] = s4.w;
    }
  }
  for (long long e = a0 + (nv << 2) + threadIdx.x; e < ce; e += blockDim.x) {
    int d = edst[e] - base;
    if ((unsigned)d < (unsigned)lim) {
      unsigned int old = atomicAdd(&cur4[d >> 2], 1u << ((d & 3) * 8));
      csr[rp[d] + bsum[(base + d) >> 8] + ((old >> ((d & 3) * 8)) & 0xff)] = esrc[e];
    }
  }
}

// ------------------------------------------------- (N,64) @ (64,64) GEMM
__global__ void __launch_bounds__(256) k_gemm64(
    const float* __restrict__ in, const float* __restrict__ norm,
    const float* __restrict__ W, float* __restrict__ out, int N) {
  __shared__ float Wl[4096];
  __shared__ float Ac[64 * 136];
  const int t = threadIdx.x;
  const int ch = (t & 7) * 8;
  const int nb = (t >> 3) * 4;
  for (int i = t; i < 1024; i += 256)
    ((float4*)Wl)[i] = ((const float4*)W)[i];
  const int NT = (N + 127) >> 7;
  for (int tile = blockIdx.x; tile < NT; tile += gridDim.x) {
    const int vbase = tile << 7;
    __syncthreads();
    for (int i = t; i < 2048; i += 256) {
      const int r = i >> 4;
      const int c = (i & 15) * 4;
      const int v = vbase + r;
      float4 val = make_float4(0.f, 0.f, 0.f, 0.f);
      if (v < N) val = *(const float4*)(in + (size_t)v * 64 + c);
      Ac[(c + 0) * 136 + r] = val.x;
      Ac[(c + 1) * 136 + r] = val.y;
      Ac[(c + 2) * 136 + r] = val.z;
      Ac[(c + 3) * 136 + r] = val.w;
    }
    __syncthreads();
    float acc[4][8];
#pragma unroll
    for (int j = 0; j < 4; ++j)
#pragma unroll
      for (int c = 0; c < 8; ++c) acc[j][c] = 0.f;
    for (int k = 0; k < 64; k += 4) {
#pragma unroll
      for (int kk = 0; kk < 4; ++kk) {
        const float4 aa = *(const float4*)&Ac[(k + kk) * 136 + nb];
        const float4 w0 = *(const float4*)&Wl[(k + kk) * 64 + ch];
        const float4 w1 = *(const float4*)&Wl[(k + kk) * 64 + ch + 4];
        const float an[4] = {aa.x, aa.y, aa.z, aa.w};
        const float wn[8] = {w0.x, w0.y, w0.z, w0.w, w1.x, w1.y, w1.z, w1.w};
#pragma unroll
        for (int j = 0; j < 4; ++j)
#pragma unroll
          for (int c = 0; c < 8; ++c)
            acc[j][c] = fmaf(an[j], wn[c], acc[j][c]);
      }
    }
#pragma unroll
    for (int j = 0; j < 4; ++j) {
      const int v = vbase + nb + j;
      if (v < N) {
        const float nm = norm[v];
        float4 o0, o1;
        o0.x = acc[j][0] * nm; o0.y = acc[j][1] * nm;
        o0.z = acc[j][2] * nm; o0.w = acc[j][3] * nm;
        o1.x = acc[j][4] * nm; o1.y = acc[j][5] * nm;
        o1.z = acc[j][6] * nm; o1.w = acc[j][7] * nm;
        *(float4*)(out + (size_t)v * 64 + ch)     = o0;
        *(float4*)(out + (size_t)v * 64 + ch + 4) = o1;
      }
    }
  }
}

// ---------------------------------------- CSR gather + fused epilogue
// PERSISTENT grid; one node per wave per iteration (8-group x 8-lane layout).
// Plain loads/stores only (nt hints regress 85% on gfx950).  h may be
// nullptr (gather2: key-only; h2 rows are re-gathered for the 3 selected
// nodes per graph inside k_tail).
__global__ void k_gather(const float* __restrict__ m, const int* __restrict__ rowptr,
                         const int* __restrict__ bsum,
                         const int* __restrict__ deg, const float* __restrict__ norm_d,
                         const float* __restrict__ bias, const int* __restrict__ csr,
                         const float* __restrict__ nsrc,
                         const int* __restrict__ gid, int* __restrict__ gstart,
                         float* __restrict__ h, float* __restrict__ key, int N) {
  const int wpb = blockDim.x >> 6;
  const int nwaves = gridDim.x * wpb;
  const int lane = threadIdx.x & 63;
  const int chb = (lane & 7) * 8;   // channel base (8 ch/lane)
  const int grp = lane >> 3;        // 8 edge subgroups
  const float4 b0 = *(const float4*)(bias + chb);
  const float4 b1 = *(const float4*)(bias + chb + 4);
  for (int w = blockIdx.x * wpb + (threadIdx.x >> 6); w < N; w += nwaves) {
    if (gid != nullptr && lane == 0) {
      int g = gid[w];
      if (w == 0 || gid[w - 1] != g) gstart[g] = w;
    }
    const int start = rowptr[w] + bsum[w >> 8];
    const int cnt = deg[w];
    float4 a00 = make_float4(0.f, 0.f, 0.f, 0.f);
    float4 a01 = make_float4(0.f, 0.f, 0.f, 0.f);
    float4 a10 = make_float4(0.f, 0.f, 0.f, 0.f);
    float4 a11 = make_float4(0.f, 0.f, 0.f, 0.f);
    int i = grp;
    if (nsrc != nullptr) {
      for (; i + 8 < cnt; i += 16) {
        int s0 = csr[start + i];
        int s1 = csr[start + i + 8];
        float n0 = nsrc[s0], n1 = nsrc[s1];
        const float* r0 = m + (size_t)s0 * 64 + chb;
        const float* r1 = m + (size_t)s1 * 64 + chb;
        const float4 v00 = *(const float4*)r0;
        const float4 v01 = *(const float4*)(r0 + 4);
        const float4 v10 = *(const float4*)r1;
        const float4 v11 = *(const float4*)(r1 + 4);
        a00.x = fmaf(v00.x, n0, a00.x); a00.y = fmaf(v00.y, n0, a00.y);
        a00.z = fmaf(v00.z, n0, a00.z); a00.w = fmaf(v00.w, n0, a00.w);
        a01.x = fmaf(v01.x, n0, a01.x); a01.y = fmaf(v01.y, n0, a01.y);
        a01.z = fmaf(v01.z, n0, a01.z); a01.w = fmaf(v01.w, n0, a01.w);
        a10.x = fmaf(v10.x, n1, a10.x); a10.y = fmaf(v10.y, n1, a10.y);
        a10.z = fmaf(v10.z, n1, a10.z); a10.w = fmaf(v10.w, n1, a10.w);
        a11.x = fmaf(v11.x, n1, a11.x); a11.y = fmaf(v11.y, n1, a11.y);
        a11.z = fmaf(v11.z, n1, a11.z); a11.w = fmaf(v11.w, n1, a11.w);
      }
      if (i < cnt) {
        int s0 = csr[start + i];
        float n0 = nsrc[s0];
        const float* r0 = m + (size_t)s0 * 64 + chb;
        const float4 v00 = *(const float4*)r0;
        const float4 v01 = *(const float4*)(r0 + 4);
        a00.x = fmaf(v00.x, n0, a00.x); a00.y = fmaf(v00.y, n0, a00.y);
        a00.z = fmaf(v00.z, n0, a00.z); a00.w = fmaf(v00.w, n0, a00.w);
        a01.x = fmaf(v01.x, n0, a01.x); a01.y = fmaf(v01.y, n0, a01.y);
        a01.z = fmaf(v01.z, n0, a01.z); a01.w = fmaf(v01.w, n0, a01.w);
      }
    } else {
      for (; i + 8 < cnt; i += 16) {
        int s0 = csr[start + i];
        int s1 = csr[start + i + 8];
        const float* r0 = m + (size_t)s0 * 64 + chb;
        const float* r1 = m + (size_t)s1 * 64 + chb;
        const float4 v00 = *(const float4*)r0;
        const float4 v01 = *(const float4*)(r0 + 4);
        const float4 v10 = *(const float4*)r1;
        const float4 v11 = *(const float4*)(r1 + 4);
        a00.x += v00.x; a00.y += v00.y; a00.z += v00.z; a00.w += v00.w;
        a01.x += v01.x; a01.y += v01.y; a01.z += v01.z; a01.w += v01.w;
        a10.x += v10.x; a10.y += v10.y; a10.z += v10.z; a10.w += v10.w;
        a11.x += v11.x; a11.y += v11.y; a11.z += v11.z; a11.w += v11.w;
      }
      if (i < cnt) {
        int s0 = csr[start + i];
        const float* r0 = m + (size_t)s0 * 64 + chb;
        const float4 v00 = *(const float4*)r0;
        const float4 v01 = *(const float4*)(r0 + 4);
        a00.x += v00.x; a00.y += v00.y; a00.z += v00.z; a00.w += v00.w;
        a01.x += v01.x; a01.y += v01.y; a01.z += v01.z; a01.w += v01.w;
      }
    }
    a00.x += a10.x; a00.y += a10.y; a00.z += a10.z; a00.w += a10.w;
    a01.x += a11.x; a01.y += a11.y; a01.z += a11.z; a01.w += a11.w;
#pragma unroll
    for (int off = 8; off <= 32; off <<= 1) {
      a00.x += __shfl_xor(a00.x, off, 64);
      a00.y += __shfl_xor(a00.y, off, 64);
      a00.z += __shfl_xor(a00.z, off, 64);
      a00.w += __shfl_xor(a00.w, off, 64);
      a01.x += __shfl_xor(a01.x, off, 64);
      a01.y += __shfl_xor(a01.y, off, 64);
      a01.z += __shfl_xor(a01.z, off, 64);
      a01.w += __shfl_xor(a01.w, off, 64);
    }
    const float nd = norm_d[w];
    float4 o0, o1;
    o0.x = fmaxf(fmaf(a00.x, nd, b0.x), 0.f);
    o0.y = fmaxf(fmaf(a00.y, nd, b0.y), 0.f);
    o0.z = fmaxf(fmaf(a00.z, nd, b0.z), 0.f);
    o0.w = fmaxf(fmaf(a00.w, nd, b0.w), 0.f);
    o1.x = fmaxf(fmaf(a01.x, nd, b1.x), 0.f);
    o1.y = fmaxf(fmaf(a01.y, nd, b1.y), 0.f);
    o1.z = fmaxf(fmaf(a01.z, nd, b1.z), 0.f);
    o1.w = fmaxf(fmaf(a01.w, nd, b1.w), 0.f);
    if (h != nullptr && grp == 0) {
      *(float4*)(h + (size_t)w * 64 + chb)     = o0;
      *(float4*)(h + (size_t)w * 64 + chb + 4) = o1;
    }
    if (key != nullptr) {
      float mx = fmaxf(fmaxf(fmaxf(o0.x, o0.y), fmaxf(o0.z, o0.w)),
                       fmaxf(fmaxf(o1.x, o1.y), fmaxf(o1.z, o1.w)));
#pragma unroll
      for (int off = 1; off < 8; off <<= 1) mx = fmaxf(mx, __shfl_xor(mx, off, 64));
      if (lane == 0) key[w] = mx;
    }
  }
}

// ---------------- fused tail: top3 + RE-GATHER of selected rows + bitonic
// sort-pool + classifier + gcnt.  Identical math/order to gather2's row
// computation -> identical h2 values, without the 25.6 MB h2 store.
__global__ void __launch_bounds__(256) k_tail(
    const float* __restrict__ key, const int* __restrict__ gstart,
    const float* __restrict__ m, const int* __restrict__ rowptr,
    const int* __restrict__ bsum, const int* __restrict__ deg,
    const float* __restrict__ norm_d, const float* __restrict__ bias,
    const int* __restrict__ csr,
    const float* __restrict__ cw, const float* __restrict__ cb,
    const float* __restrict__ Wc, const float* __restrict__ bc,
    float* __restrict__ out, int B, int N) {
  __shared__ int sel[3];
  __shared__ float prow[192];
  const int b = blockIdx.x;
  const int wid = threadIdx.x >> 6;
  const int lane = threadIdx.x & 63;

  if (wid == 0) {
    const int gs = gstart[b];
    int g2 = b + 1;
    while (g2 < B && gstart[g2] >= N) ++g2;   // skip empty graphs (sentinel)
    const int ns = (g2 < B) ? gstart[g2] : N;
    const int s = gs;
    const int c = (gs < N) ? (ns - gs) : 0;
    float v0 = -1.f, v1 = -1.f, v2 = -1.f;
    int i0 = 0x7fffffff, i1 = 0x7fffffff, i2 = 0x7fffffff;
    for (int i = s + lane; i < s + c; i += 64) {
      float kv = key[i];
      if (kv > v0 || (kv == v0 && i < i0)) {
        v2 = v1; i2 = i1; v1 = v0; i1 = i0; v0 = kv; i0 = i;
      } else if (kv > v1 || (kv == v1 && i < i1)) {
        v2 = v1; i2 = i1; v1 = kv; i1 = i;
      } else if (kv > v2 || (kv == v2 && i < i2)) {
        v2 = kv; i2 = i;
      }
    }
    int ptr = 0;
    for (int r = 0; r < 3; ++r) {
      float mv = (ptr == 0) ? v0 : (ptr == 1) ? v1 : (ptr == 2) ? v2 : -1.f;
      int   mi = (ptr == 0) ? i0 : (ptr == 1) ? i1 : (ptr == 2) ? i2 : 0x7fffffff;
      float bv = mv; int bi = mi;
#pragma unroll
      for (int off = 32; off; off >>= 1) {
        float ov = __shfl_xor(bv, off, 64);
        int   oi = __shfl_xor(bi, off, 64);
        if (ov > bv || (ov == bv && oi < bi)) { bv = ov; bi = oi; }
      }
      if (bi == mi && ptr < 3) ptr++;             // winner's owner pops
      if (lane == 0) sel[r] = (bi == 0x7fffffff) ? -1 : bi;
    }
  }
  __syncthreads();
  // re-gather selected rows (same layout + reduce tree as k_gather)
  if (wid < 3) {
    const int node = sel[wid];
    if (node >= 0) {
      const int chb = (lane & 7) * 8;
      const int grp = lane >> 3;
      const int start = rowptr[node] + bsum[node >> 8];
      const int cnt = deg[node];
      float4 a00 = make_float4(0.f, 0.f, 0.f, 0.f);
      float4 a01 = make_float4(0.f, 0.f, 0.f, 0.f);
      float4 a10 = make_float4(0.f, 0.f, 0.f, 0.f);
      float4 a11 = make_float4(0.f, 0.f, 0.f, 0.f);
      int i = grp;
      for (; i + 8 < cnt; i += 16) {
        int s0 = csr[start + i];
        int s1 = csr[start + i + 8];
        const float* r0 = m + (size_t)s0 * 64 + chb;
        const float* r1 = m + (size_t)s1 * 64 + chb;
        const float4 v00 = *(const float4*)r0;
        const float4 v01 = *(const float4*)(r0 + 4);
        const float4 v10 = *(const float4*)r1;
        const float4 v11 = *(const float4*)(r1 + 4);
        a00.x += v00.x; a00.y += v00.y; a00.z += v00.z; a00.w += v00.w;
        a01.x += v01.x; a01.y += v01.y; a01.z += v01.z; a01.w += v01.w;
        a10.x += v10.x; a10.y += v10.y; a10.z += v10.z; a10.w += v10.w;
        a11.x += v11.x; a11.y += v11.y; a11.z += v11.z; a11.w += v11.w;
      }
      if (i < cnt) {
        int s0 = csr[start + i];
        const float* r0 = m + (size_t)s0 * 64 + chb;
        const float4 v00 = *(const float4*)r0;
        const float4 v01 = *(const float4*)(r0 + 4);
        a00.x += v00.x; a00.y += v00.y; a00.z += v00.z; a00.w += v00.w;
        a01.x += v01.x; a01.y += v01.y; a01.z += v01.z; a01.w += v01.w;
      }
      a00.x += a10.x; a00.y += a10.y; a00.z += a10.z; a00.w += a10.w;
      a01.x += a11.x; a01.y += a11.y; a01.z += a11.z; a01.w += a11.w;
#pragma unroll
      for (int off = 8; off <= 32; off <<= 1) {
        a00.x += __shfl_xor(a00.x, off, 64);
        a00.y += __shfl_xor(a00.y, off, 64);
        a00.z += __shfl_xor(a00.z, off, 64);
        a00.w += __shfl_xor(a00.w, off, 64);
        a01.x += __shfl_xor(a01.x, off, 64);
        a01.y += __shfl_xor(a01.y, off, 64);
        a01.z += __shfl_xor(a01.z, off, 64);
        a01.w += __shfl_xor(a01.w, off, 64);
      }
      const float nd = norm_d[node];
      const float4 b0 = *(const float4*)(bias + chb);
      const float4 b1 = *(const float4*)(bias + chb + 4);
      float4 o0, o1;
      o0.x = fmaxf(fmaf(a00.x, nd, b0.x), 0.f);
      o0.y = fmaxf(fmaf(a00.y, nd, b0.y), 0.f);
      o0.z = fmaxf(fmaf(a00.z, nd, b0.z), 0.f);
      o0.w = fmaxf(fmaf(a00.w, nd, b0.w), 0.f);
      o1.x = fmaxf(fmaf(a01.x, nd, b1.x), 0.f);
      o1.y = fmaxf(fmaf(a01.y, nd, b1.y), 0.f);
      o1.z = fmaxf(fmaf(a01.z, nd, b1.z), 0.f);
      o1.w = fmaxf(fmaf(a01.w, nd, b1.w), 0.f);
      if (grp == 0) {
        *(float4*)&prow[wid * 64 + chb]     = o0;
        *(float4*)&prow[wid * 64 + chb + 4] = o1;
      }
    } else {
      prow[wid * 64 + lane] = 0.f;
    }
  }
  __syncthreads();
  if (wid < 3) {
    float v = prow[wid * 64 + lane];
    if (sel[wid] >= 0) {
      for (int k2 = 2; k2 <= 64; k2 <<= 1) {
        for (int j = k2 >> 1; j > 0; j >>= 1) {
          float o = __shfl_xor(v, j, 64);
          bool up = ((lane & k2) == 0);
          bool lower = ((lane & j) == 0);
          v = (lower == up) ? fminf(v, o) : fmaxf(v, o);
        }
      }
    }
    prow[wid * 64 + lane] = v;
  }
  __syncthreads();
  if (wid == 0) {
    float y = cb[lane];
    for (int j = 0; j < 192; ++j) y = fmaf(prow[j], cw[lane * 192 + j], y);
    float ry = fmaxf(y, 0.f);
    for (int c = 0; c < 10; ++c) {
      float s = ry * Wc[lane * 10 + c];
#pragma unroll
      for (int off = 32; off; off >>= 1) s += __shfl_xor(s, off, 64);
      if (lane == 0) out[b * 10 + c] = s + bc[c];
    }
  }
}

// ================================================================ launch
extern "C" void kernel_launch(void* const* d_in, const int* in_sizes, int n_in,
                              void* d_out, int out_size, void* d_ws, size_t ws_size,
                              hipStream_t stream) {
  const float* features = (const float*)d_in[0];
  const int*   esrc     = (const int*)d_in[1];
  const int*   edst     = (const int*)d_in[2];
  const int*   gid      = (const int*)d_in[3];
  const float* W1 = (const float*)d_in[5];
  const float* b1 = (const float*)d_in[6];
  const float* W2 = (const float*)d_in[7];
  const float* b2 = (const float*)d_in[8];
  const float* cw = (const float*)d_in[9];
  const float* cb = (const float*)d_in[10];
  const float* Wc = (const float*)d_in[11];
  const float* bc = (const float*)d_in[12];
  float* out = (float*)d_out;

  const int N = in_sizes[0] / 64;
  const int E = in_sizes[1];
  const int B = out_size / 10;
  const size_t N64 = (size_t)N * 64;
  const int nscan = (N + 255) / 256;            // 391 for N=100k (<= 512)
  const int PH = (N + PART_H - 1) / PART_H;     // 2 for N=100k
  const int PF = (N + PART_F - 1) / PART_F;     // 4 for N=100k
  const size_t HSZD = (size_t)PH * MCH  * PART_H; // hd bytes (~12.8 MB)
  const size_t HSZS = (size_t)PH * MCHS * PART_H; // hs bytes (~3.2 MB)
  const int NT = (N + 127) / 128;               // gemm tiles
  const int histBlocks = PH * (MCH + MCHS);     // 320

  // workspace carve-up (fully disjoint).
  float* bufA   = (float*)d_ws;            // N*64 : m1 -> m2
  float* bufB   = bufA + N64;              // N*64 : h1
  int*   deg_d  = (int*)(bufB + N64);      // N
  float* norm_s = (float*)(deg_d + N);     // N
  float* norm_d = norm_s + N;              // N
  float* key    = norm_d + N;              // N
  int*   rowptr = (int*)(key + N);         // N
  int*   csr    = rowptr + N;              // E
  int*   bsum   = csr + E;                 // <=512
  int*   gstart = bsum + 512;              // B
  // align hd to 16 B for the u64/uint4-vectorized passes
  unsigned char* hd = (unsigned char*)(((size_t)(gstart + B) + 15) & ~(size_t)15);
  unsigned char* hs = hd + HSZD;                     // HSZS u8

  const int TB = 256;

  // ---- CSR build overlapped with gemm1 (un-normed; norm_s applied in gather1)
  k_histgemm<<<histBlocks + NT, TB, 0, stream>>>(esrc, edst, hd, hs,
                                                 features, W1, bufA,
                                                 N, E, PH, histBlocks);
  k_offscan<<<nscan, 256, 0, stream>>>(hd, hs, deg_d, norm_s, norm_d,
                                       gstart, rowptr, bsum, B, N);
  k_scan2<<<1, 512, 0, stream>>>(bsum, nscan);
  k_fill2<<<PF * MCH, TB, 0, stream>>>(esrc, edst, hd, rowptr, bsum, csr, N, E, PF);

  // ---- gathers: persistent grid (8 blocks/CU resident on 256 CUs)
  const int GB = 2048;

  // ---- layer 1 gather (applies norm_s per source) -> h1 (bufB)
  k_gather<<<GB, TB, 0, stream>>>(bufA, rowptr, bsum, deg_d, norm_d, b1,
                                  csr, norm_s, nullptr, nullptr,
                                  bufB, nullptr, N);

  // ---- layer 2: gemm -> m2 (bufA), gather2 -> key only (+ gstart)
  k_gemm64<<<NT, TB, 0, stream>>>(bufB, norm_s, W2, bufA, N);
  k_gather<<<GB, TB, 0, stream>>>(bufA, rowptr, bsum, deg_d, norm_d, b2,
                                  csr, nullptr, gid, gstart,
                                  nullptr, key, N);

  // ---- pooling + classifier (tail re-gathers the 3 selected rows/graph)
  k_tail<<<B, TB, 0, stream>>>(key, gstart, bufA, rowptr, bsum, deg_d,
                               norm_d, b2, csr, cw, cb, Wc, bc, out, B, N);
}